// Round 6
// baseline (105.155 us; speedup 1.0000x reference)
//
#include <hip/hip_runtime.h>
#include <hip/hip_fp16.h>

#define B_SZ    16384
#define NNZ_PER 32
#define F_DIM   768
#define H_DIM   512
#define SLICE_H 64
#define NSLICE  8
#define CHUNK   256
#define ROWB    80          // LDS row stride: 16B-aligned; f*80 fits 16 bits

typedef unsigned int  uint32;
typedef unsigned char uchar;

// ws layout (bytes)
#define WT8_OFF  0u                          // [NSLICE][F][64] e5m2 = 393216
#define PK_OFF   393216u                     // [B][64] uint32 = 4 MiB
#define PART_OFF (393216u + 4194304u)        // [NSLICE][B] f32 = 512 KiB

__device__ inline uchar f32_to_e5m2(float x) {
    __half h = __float2half_rn(x);
    unsigned short hb = *(unsigned short*)&h;
    unsigned short lsb = (hb >> 8) & 1;
    hb = (unsigned short)(hb + 0x7F + lsb);   // RNE into top 8 bits
    return (uchar)(hb >> 8);
}

// ---------------------------------------------------------------------------
// Fused prep: blocks 0..383 transpose+quantize W; blocks 384..4479 pack entries.
// ---------------------------------------------------------------------------
__global__ __launch_bounds__(256) void prep(
    const float* __restrict__ W,
    const int*   __restrict__ stm_idx,
    const int*   __restrict__ nstm_idx,
    const float* __restrict__ stm_val,
    const float* __restrict__ nstm_val,
    uchar*  __restrict__ Wt8,
    uint32* __restrict__ packed)
{
    if (blockIdx.x < 384) {
        // transpose W_ft [H][F] fp32 -> Wt8 [slice][F][64] e5m2
        __shared__ float tile[32][33];
        const int bx = blockIdx.x % 24;       // f tile
        const int by = blockIdx.x / 24;       // h tile
        const int f0 = bx * 32, h0 = by * 32;
        const int tx = threadIdx.x & 31;
        const int ty = threadIdx.x >> 5;      // 0..7

#pragma unroll
        for (int i = 0; i < 32; i += 8)
            tile[ty + i][tx] = W[(h0 + ty + i) * F_DIM + f0 + tx];
        __syncthreads();
        const int s = h0 >> 6;
#pragma unroll
        for (int i = 0; i < 32; i += 8) {
            const int f = f0 + ty + i;
            const int h = h0 + tx;
            Wt8[(size_t)s * (F_DIM * SLICE_H) + f * SLICE_H + (h & 63)] =
                f32_to_e5m2(tile[tx][ty + i]);
        }
    } else {
        // pack {f*ROWB | fp16(v)<<16}
        const int e = (blockIdx.x - 384) * 256 + threadIdx.x;  // 0 .. B*64
        const int b = e >> 6, j = e & 63;
        const int NNZ = B_SZ * NNZ_PER;
        int f; float v;
        if (j < 32) { f = stm_idx [NNZ + b * 32 + j];        v = stm_val [b * 32 + j]; }
        else        { f = nstm_idx[NNZ + b * 32 + (j - 32)]; v = nstm_val[b * 32 + (j - 32)]; }
        __half hv = __float2half_rn(v);
        packed[e] = (uint32)(unsigned short)(f * ROWB) |
                    ((uint32)(*(unsigned short*)&hv) << 16);
    }
}

// ---------------------------------------------------------------------------
// Main: grid (64 chunks, 8 slices), 1024 threads (16 waves), FORCED 2 blocks/CU
// (launch_bounds caps VGPR at 64 -> 32 waves/CU for LDS latency hiding).
// Stage 48 KB W-slice into LDS (stride 80B); wave handles 16 positions x 4
// h-subslices; gather rows via ds_read_b128, e5m2->fp16 perm decode, hfma2.
// ---------------------------------------------------------------------------
__global__ __launch_bounds__(1024, 8) void nnue_main(
    const uchar*  __restrict__ Wt8,
    const uint32* __restrict__ packed,
    const float*  __restrict__ b_ft,
    const float*  __restrict__ W_out,
    float* __restrict__ partials)
{
    __shared__ uchar Wl[F_DIM * ROWB];    // 61440 B -> 2 blocks/CU
    const int tid   = threadIdx.x;
    const int chunk = blockIdx.x;
    const int s     = blockIdx.y;

    {
        const uchar* src = Wt8 + (size_t)s * (F_DIM * SLICE_H);
#pragma unroll
        for (int pass = 0; pass < 3; ++pass) {
            const int o = pass * 16384 + tid * 16;
            const int f = o >> 6, col = o & 63;
            uint4 v = *(const uint4*)(src + o);
            *(uint4*)(&Wl[f * ROWB + col]) = v;
        }
    }
    __syncthreads();

    const int w    = tid >> 6;
    const int lane = tid & 63;
    const int hs   = lane & 3;
    const int pl   = lane >> 2;
    const int pos  = chunk * CHUNK + w * 16 + pl;
    const int hb   = hs * 16;

    const uint4* pk4 = (const uint4*)(packed + pos * 64);

    const uint32 selA = 0x01040004u;
    const uint32 selB = 0x03040204u;

    __half2 z = __float2half2_rn(0.f);
    __half2 sa[8] = {z,z,z,z,z,z,z,z};
    __half2 na[8] = {z,z,z,z,z,z,z,z};

#define PROC1(acc, e)                                                         \
    {                                                                         \
        const uint32 off = (e & 0xFFFFu) + (uint32)hb;                        \
        uint32 vvb = __builtin_amdgcn_perm(e, e, 0x03020302u);                \
        __half2 vv = *(__half2*)&vvb;                                         \
        uint4 wv = *(const uint4*)(&Wl[off]);                                 \
        uint32 p;                                                             \
        p = __builtin_amdgcn_perm(0u, wv.x, selA); acc[0] = __hfma2(*(__half2*)&p, vv, acc[0]); \
        p = __builtin_amdgcn_perm(0u, wv.x, selB); acc[1] = __hfma2(*(__half2*)&p, vv, acc[1]); \
        p = __builtin_amdgcn_perm(0u, wv.y, selA); acc[2] = __hfma2(*(__half2*)&p, vv, acc[2]); \
        p = __builtin_amdgcn_perm(0u, wv.y, selB); acc[3] = __hfma2(*(__half2*)&p, vv, acc[3]); \
        p = __builtin_amdgcn_perm(0u, wv.z, selA); acc[4] = __hfma2(*(__half2*)&p, vv, acc[4]); \
        p = __builtin_amdgcn_perm(0u, wv.z, selB); acc[5] = __hfma2(*(__half2*)&p, vv, acc[5]); \
        p = __builtin_amdgcn_perm(0u, wv.w, selA); acc[6] = __hfma2(*(__half2*)&p, vv, acc[6]); \
        p = __builtin_amdgcn_perm(0u, wv.w, selB); acc[7] = __hfma2(*(__half2*)&p, vv, acc[7]); \
    }

#pragma unroll
    for (int jg = 0; jg < 8; ++jg) {          // stm entries 0..31
        uint4 cur = pk4[jg];
        PROC1(sa, cur.x); PROC1(sa, cur.y); PROC1(sa, cur.z); PROC1(sa, cur.w);
    }
#pragma unroll
    for (int jg = 8; jg < 16; ++jg) {         // nstm entries 32..63
        uint4 cur = pk4[jg];
        PROC1(na, cur.x); PROC1(na, cur.y); PROC1(na, cur.z); PROC1(na, cur.w);
    }
#undef PROC1

    const int h0 = s * SLICE_H + hb;
    float dot = 0.f;
#pragma unroll
    for (int i = 0; i < 8; ++i) {
        float2 bi  = *(const float2*)(b_ft  + h0 + 2 * i);
        float2 wsv = *(const float2*)(W_out + h0 + 2 * i);
        float2 wnv = *(const float2*)(W_out + H_DIM + h0 + 2 * i);
        float a0 = fminf(fmaxf(__low2float (sa[i]) + bi.x, 0.f), 1.f);
        float a1 = fminf(fmaxf(__high2float(sa[i]) + bi.y, 0.f), 1.f);
        float c0 = fminf(fmaxf(__low2float (na[i]) + bi.x, 0.f), 1.f);
        float c1 = fminf(fmaxf(__high2float(na[i]) + bi.y, 0.f), 1.f);
        dot += a0 * wsv.x + a1 * wsv.y + c0 * wnv.x + c1 * wnv.y;
    }
    dot += __shfl_xor(dot, 1, 64);
    dot += __shfl_xor(dot, 2, 64);
    if (hs == 0) partials[s * B_SZ + pos] = dot;
}

__global__ __launch_bounds__(256) void finalize(
    const float* __restrict__ partials,
    const float* __restrict__ b_out,
    float* __restrict__ out)
{
    const int b = blockIdx.x * 256 + threadIdx.x;
    float a = b_out[0];
#pragma unroll
    for (int s = 0; s < NSLICE; ++s)
        a += partials[s * B_SZ + b];
    out[b] = 1.f / (1.f + expf(-a));
}

extern "C" void kernel_launch(void* const* d_in, const int* in_sizes, int n_in,
                              void* d_out, int out_size, void* d_ws, size_t ws_size,
                              hipStream_t stream) {
    const int*   stm_idx  = (const int*)  d_in[0];
    const int*   nstm_idx = (const int*)  d_in[1];
    const float* stm_val  = (const float*)d_in[2];
    const float* nstm_val = (const float*)d_in[3];
    const float* W_ft     = (const float*)d_in[5];
    const float* b_ft     = (const float*)d_in[6];
    const float* W_out    = (const float*)d_in[7];
    const float* b_out    = (const float*)d_in[8];
    float*       out      = (float*)d_out;

    uchar*  Wt8      = (uchar*) ((char*)d_ws + WT8_OFF);
    uint32* packed   = (uint32*)((char*)d_ws + PK_OFF);
    float*  partials = (float*) ((char*)d_ws + PART_OFF);

    prep<<<384 + (B_SZ * 64) / 256, 256, 0, stream>>>(
        W_ft, stm_idx, nstm_idx, stm_val, nstm_val, Wt8, packed);

    dim3 grid(B_SZ / CHUNK, NSLICE);          // 64 x 8 = 512 blocks
    nnue_main<<<grid, 1024, 0, stream>>>(Wt8, packed, b_ft, W_out, partials);

    finalize<<<B_SZ / 256, 256, 0, stream>>>(partials, b_out, out);
}